// Round 10
// baseline (402.961 us; speedup 1.0000x reference)
//
#include <hip/hip_runtime.h>

// Problem constants: E=800000 (=3125*256), N=50000, G=16, EMB=64.
#define EMB  64
#define NREP 256   // replica lines for per-graph global atomic spreading

typedef __attribute__((ext_vector_type(8))) short bf16x8;
typedef __attribute__((ext_vector_type(4))) float f32x4;
union BF8 { bf16x8 v; short s[8]; unsigned u[4]; };

// float -> bf16 bits, round-to-nearest-even (finite inputs).
static __device__ __forceinline__ short f2bf(float f) {
    unsigned u = __float_as_uint(f);
    u += 0x7fffu + ((u >> 16) & 1u);
    return (short)(u >> 16);
}

// 2x float -> packed bf16 pair in one instruction (RNE, bit-identical to f2bf).
static __device__ __forceinline__ unsigned cvt2(float lo, float hi) {
    unsigned r;
    asm("v_cvt_pk_bf16_f32 %0, %1, %2" : "=v"(r) : "v"(lo), "v"(hi));
    return r;
}

// ---------------------------------------------------------------------------
// Prep: ecnt histogram, scalar 1-edge/thread. (R9 exonerated the int4
// variant -- R7's +38us was container variance on fill -- but scalar is
// equivalent and simpler; keeping it.)
// ---------------------------------------------------------------------------
__global__ __launch_bounds__(256) void prep_kernel(
    const int* __restrict__ eidx, int* __restrict__ ecnt, int E)
{
    int t = blockIdx.x * 256 + threadIdx.x;
    if (t < E) atomicAdd(&ecnt[eidx[t]], 1);
}

// ---------------------------------------------------------------------------
// Edge kernel v10 = v9 with the cross-quad shfl reduce REPLACED by direct
// per-quad LDS float atomics (fire-and-forget ds_add_f32).
// R9 analysis: edge 125.5us @ VALUBusy 58%, ~42% bubbles; in-loop stall
// sources are MFMA->silu latency and the 12 shfl_xor(16/32) per nt whose
// results feed dependent adds (2-deep wait chain, all 3 waves in lockstep).
// v10: every quad adds its partial acc_c * scl into bins[g*6+c]; quad 0
// alone folds in bb2*scl. Sum is value-identical:
//   Sum_quads(acc_q_c)*scl + bb2*scl = (full_acc_c + bb2)*scl.
// Deletes 48 shfl + 12 adds per wave-iter and the dummy-bin trick; 6
// wave-wide DS atomics per nt replace 15 DS insts, with NO result wait.
// REGISTER-CAP RULE stands (R4/R5/R8): (256,3) only; WRITE_SIZE must stay
// exactly 1171.875 KB (repsum flush), else spill => invalid config.
// ---------------------------------------------------------------------------
__global__ __launch_bounds__(256, 3) void edge_kernel(
    const float* __restrict__ dvec, const float* __restrict__ x_edge,
    const int*   __restrict__ eidx, const int* __restrict__ batch,
    const int*   __restrict__ ecnt,
    const float* __restrict__ W1, const float* __restrict__ b1,
    const float* __restrict__ W2, const float* __restrict__ b2,
    float* __restrict__ repsum, int E)
{
    __shared__ float bins[96];
    __shared__ float sb1N[64], sw2[64], sw2b[64];
    const int tid = threadIdx.x;
    const float NL2E = -1.442695040888963f;  // -log2(e)
    if (tid < 96) bins[tid] = 0.f;
    if (tid < 64) {
        float b = b1[tid], w = W2[tid];
        sb1N[tid] = b * NL2E;   // pre-folded exp2 bias
        sw2[tid]  = w;
        sw2b[tid] = w * b;      // pre-folded w2*z bias
    }
    __syncthreads();

    const int lane = tid & 63, wave = tid >> 6;
    const int col  = lane & 15, quad = lane >> 4;
    const long ebase = (long)blockIdx.x * 256 + wave * 64;

    // --- Prologue 1: scatter-metadata chain issued early, ALL lanes
    // (e depends only on col; quads 2/3 hit identical addresses).
    int nn[4];
    #pragma unroll
    for (int nt = 0; nt < 4; ++nt) {
        long e = ebase + nt * 16 + col;
        if (e >= E) e = 0;
        nn[nt] = eidx[e];
    }

    // --- Prologue 2: A fragments (W1 is 16KB, L2-hot).
    // A[m=mt*16+col][k=kt*32+quad*8+j] = W1[k][m]  (bf16 RNE)
    BF8 Af[4][2];
    #pragma unroll
    for (int mt = 0; mt < 4; ++mt)
        #pragma unroll
        for (int kt = 0; kt < 2; ++kt) {
            const float* wp = W1 + (kt * 32 + quad * 8) * 64 + mt * 16 + col;
            #pragma unroll
            for (int j = 0; j < 8; ++j) Af[mt][kt].s[j] = f2bf(wp[j * 64]);
        }

    // --- Prologue 3: resolve metadata; per-nt scatter base + scale.
    // All quads scatter partials; quad 0 additionally owns the bb2 term.
    float scl[4];
    int   tb[4];
    #pragma unroll
    for (int nt = 0; nt < 4; ++nt) {
        long e = ebase + nt * 16 + col;
        float s = __builtin_amdgcn_rcpf((float)max(ecnt[nn[nt]], 1));
        scl[nt] = (e < E) ? s : 0.f;
        tb[nt]  = batch[nn[nt]] * 6;
    }

    const float bb2q = (quad == 0) ? b2[0] : 0.f;   // bb2 folded once per edge

// Issue x/dvec loads for sub-tile NT into one stage register set (19 regs).
#define PIPE_ISSUE(NT, XA, XB, XC, XD, DD0, DD1, DD2)                          \
    {                                                                          \
        long e_ = ebase + (NT) * 16 + col;                                     \
        if (e_ >= E) e_ = 0;                                                   \
        const float* xp_ = x_edge + (size_t)e_ * EMB + quad * 8;               \
        XA = *(const f32x4*)(xp_);                                             \
        XB = *(const f32x4*)(xp_ + 4);                                         \
        XC = *(const f32x4*)(xp_ + 32);                                        \
        XD = *(const f32x4*)(xp_ + 36);                                        \
        DD0 = dvec[3 * e_ + 0];                                                \
        DD1 = dvec[3 * e_ + 1];                                                \
        DD2 = dvec[3 * e_ + 2];                                                \
    }

// Consume one stage; PRE (next stage's PIPE_ISSUE) sits after the B
// conversion so its load latency hides under the MFMA+silu block.
// Epilogue: 6 fire-and-forget LDS float atomics (per-quad partials).
#define PIPE_BODY(NT, XA, XB, XC, XD, DD0, DD1, DD2, PRE)                      \
    {                                                                          \
        BF8 B0_, B1_;                                                          \
        B0_.u[0] = cvt2(XA.x, XA.y); B0_.u[1] = cvt2(XA.z, XA.w);              \
        B0_.u[2] = cvt2(XB.x, XB.y); B0_.u[3] = cvt2(XB.z, XB.w);              \
        B1_.u[0] = cvt2(XC.x, XC.y); B1_.u[1] = cvt2(XC.z, XC.w);              \
        B1_.u[2] = cvt2(XD.x, XD.y); B1_.u[3] = cvt2(XD.z, XD.w);              \
        float a_[6] = { DD0*DD0, DD1*DD1, DD2*DD2, DD0*DD1, DD0*DD2, DD1*DD2 };\
        float aN_[6];                                                          \
        _Pragma("unroll")                                                      \
        for (int c = 0; c < 6; ++c) aN_[c] = a_[c] * NL2E;                     \
        PRE                                                                    \
        float acc_[6] = { 0.f, 0.f, 0.f, 0.f, 0.f, 0.f };                      \
        _Pragma("unroll")                                                      \
        for (int mt = 0; mt < 4; ++mt) {                                       \
            f32x4 D_ = { 0.f, 0.f, 0.f, 0.f };                                 \
            D_ = __builtin_amdgcn_mfma_f32_16x16x32_bf16(Af[mt][0].v, B0_.v, D_, 0, 0, 0); \
            D_ = __builtin_amdgcn_mfma_f32_16x16x32_bf16(Af[mt][1].v, B1_.v, D_, 0, 0, 0); \
            _Pragma("unroll")                                                  \
            for (int r = 0; r < 4; ++r) {                                      \
                int   o_  = mt * 16 + quad * 4 + r;                            \
                float y_  = D_[r];                                             \
                float bN_ = sb1N[o_];                                          \
                float wy_ = sw2[o_] * y_;                                      \
                float wb_ = sw2b[o_];                                          \
                _Pragma("unroll")                                              \
                for (int c = 0; c < 6; ++c) {                                  \
                    float arg_ = fmaf(aN_[c], y_, bN_);                        \
                    float ex_  = __builtin_amdgcn_exp2f(arg_);                 \
                    float rr_  = __builtin_amdgcn_rcpf(1.0f + ex_);            \
                    float w2z_ = fmaf(a_[c], wy_, wb_);                        \
                    acc_[c]    = fmaf(w2z_, rr_, acc_[c]);                     \
                }                                                              \
            }                                                                  \
        }                                                                      \
        _Pragma("unroll")                                                      \
        for (int c = 0; c < 6; ++c)                                            \
            atomicAdd(&bins[tb[NT] + c], (acc_[c] + bb2q) * scl[NT]);          \
    }

    f32x4 Pxa, Pxb, Pxc, Pxd; float Pd0, Pd1, Pd2;
    f32x4 Qxa, Qxb, Qxc, Qxd; float Qd0, Qd1, Qd2;

    PIPE_ISSUE(0, Pxa, Pxb, Pxc, Pxd, Pd0, Pd1, Pd2)
    PIPE_BODY(0, Pxa, Pxb, Pxc, Pxd, Pd0, Pd1, Pd2,
              PIPE_ISSUE(1, Qxa, Qxb, Qxc, Qxd, Qd0, Qd1, Qd2))
    PIPE_BODY(1, Qxa, Qxb, Qxc, Qxd, Qd0, Qd1, Qd2,
              PIPE_ISSUE(2, Pxa, Pxb, Pxc, Pxd, Pd0, Pd1, Pd2))
    PIPE_BODY(2, Pxa, Pxb, Pxc, Pxd, Pd0, Pd1, Pd2,
              PIPE_ISSUE(3, Qxa, Qxb, Qxc, Qxd, Qd0, Qd1, Qd2))
    PIPE_BODY(3, Qxa, Qxb, Qxc, Qxd, Qd0, Qd1, Qd2, )

#undef PIPE_ISSUE
#undef PIPE_BODY

    __syncthreads();
    if (tid < 96) {
        int rep = blockIdx.x & (NREP - 1);
        atomicAdd(repsum + (size_t)rep * 96 + tid, bins[tid]);
    }
}

// ---------------------------------------------------------------------------
// Final: sum replicas (4-way parallel over reps); graph boundaries via
// binary search on the sorted batch array; divide by node count; expand 6
// symmetric comps -> 9.
// ---------------------------------------------------------------------------
__global__ __launch_bounds__(384) void final_kernel(
    const float* __restrict__ repsum, const int* __restrict__ batch,
    float* __restrict__ out, int N)
{
    __shared__ float part[4][96];
    __shared__ float sh[96];
    __shared__ int gs[17];
    int t = threadIdx.x;            // 384 threads
    int r0 = t / 96, gc = t % 96;   // r0 in 0..3
    if (t < 17) {
        // lower_bound: first i with batch[i] >= t  (batch sorted, 16 graphs)
        int lo = 0, hi = N;
        while (lo < hi) {
            int mid = (lo + hi) >> 1;
            if (batch[mid] < t) lo = mid + 1; else hi = mid;
        }
        gs[t] = lo;
    }
    float s = 0.f;
    #pragma unroll 8
    for (int r = r0; r < NREP; r += 4) s += repsum[(size_t)r * 96 + gc];
    part[r0][gc] = s;
    __syncthreads();
    if (t < 96) sh[t] = part[0][t] + part[1][t] + part[2][t] + part[3][t];
    __syncthreads();
    if (t < 16) {
        int gN = gs[t + 1] - gs[t];
        float inv = 1.0f / fmaxf((float)gN, 1.0f);
        float m0 = sh[t * 6 + 0] * inv;
        float m1 = sh[t * 6 + 1] * inv;
        float m2 = sh[t * 6 + 2] * inv;
        float m3 = sh[t * 6 + 3] * inv;
        float m4 = sh[t * 6 + 4] * inv;
        float m5 = sh[t * 6 + 5] * inv;
        float* p = out + t * 9;
        p[0] = m0; p[1] = m3; p[2] = m4;
        p[3] = m3; p[4] = m1; p[5] = m5;
        p[6] = m4; p[7] = m5; p[8] = m2;
    }
}

// ---------------------------------------------------------------------------
extern "C" void kernel_launch(void* const* d_in, const int* in_sizes, int n_in,
                              void* d_out, int out_size, void* d_ws, size_t ws_size,
                              hipStream_t stream) {
    const float* dvec   = (const float*)d_in[0];   // [E,3]
    const float* x_edge = (const float*)d_in[1];   // [E,64]
    const int*   eidx   = (const int*)d_in[2];     // [E]
    const int*   batch  = (const int*)d_in[3];     // [N] sorted
    const float* W1     = (const float*)d_in[6];   // [64,64] (in,out)
    const float* b1     = (const float*)d_in[7];   // [64]
    const float* W2     = (const float*)d_in[8];   // [64,1]
    const float* b2     = (const float*)d_in[9];   // [1]

    int E = in_sizes[0] / 3;   // 800000
    int N = in_sizes[3];       // 50000

    // ws: ecnt[N] int | repsum[NREP*96] float  (contiguous)
    int*   ecnt   = (int*)d_ws;
    float* repsum = (float*)(ecnt + N);

    hipMemsetAsync(d_ws, 0, ((size_t)N + (size_t)NREP * 96) * 4, stream);

    int blocks = (E + 255) / 256;   // 3125
    prep_kernel<<<blocks, 256, 0, stream>>>(eidx, ecnt, E);
    edge_kernel<<<blocks, 256, 0, stream>>>(dvec, x_edge, eidx, batch, ecnt,
                                            W1, b1, W2, b2, repsum, E);
    final_kernel<<<1, 384, 0, stream>>>(repsum, batch, (float*)d_out, N);
}

// Round 11
// 381.010 us; speedup vs baseline: 1.0576x; 1.0576x over previous
//
#include <hip/hip_runtime.h>

// Problem constants: E=800000 (=3125*256), N=50000, G=16, EMB=64.
#define EMB  64
#define NREP 256   // replica lines for per-graph global atomic spreading

typedef __attribute__((ext_vector_type(8))) short bf16x8;
typedef __attribute__((ext_vector_type(4))) float f32x4;
union BF8 { bf16x8 v; short s[8]; unsigned u[4]; };

// float -> bf16 bits, round-to-nearest-even (finite inputs).
static __device__ __forceinline__ short f2bf(float f) {
    unsigned u = __float_as_uint(f);
    u += 0x7fffu + ((u >> 16) & 1u);
    return (short)(u >> 16);
}

// 2x float -> packed bf16 pair in one instruction (RNE, bit-identical to f2bf).
static __device__ __forceinline__ unsigned cvt2(float lo, float hi) {
    unsigned r;
    asm("v_cvt_pk_bf16_f32 %0, %1, %2" : "=v"(r) : "v"(lo), "v"(hi));
    return r;
}

// ---------------------------------------------------------------------------
// Prep: ecnt histogram, scalar 1-edge/thread (validated form).
// ---------------------------------------------------------------------------
__global__ __launch_bounds__(256) void prep_kernel(
    const int* __restrict__ eidx, int* __restrict__ ecnt, int E)
{
    int t = blockIdx.x * 256 + threadIdx.x;
    if (t < E) atomicAdd(&ecnt[eidx[t]], 1);
}

// ---------------------------------------------------------------------------
// Edge kernel v11 = v9 (validated: 125.5us, VALUBusy 58%, VGPR 84, no spill)
// with ONE change: per-(mt,quad) silu constants read as f32x4/ds_read_b128
// (3 per mt, 12 per nt) instead of 48 scalar ds_read_b32 per nt. The 4 o
// values per (mt,quad) are consecutive -> natural 16B reads.
// R10 lesson: LDS-atomic scatter REGRESSED (150.6us; 4-way same-address RMW
// serialization on the DS pipe) -> shfl reduce restored.
// REGISTER-CAP RULE stands (R4/R5/R8): (256,3) only, natural allocation;
// WRITE_SIZE must stay exactly 1171.875 KB else spill => invalid config.
// ---------------------------------------------------------------------------
__global__ __launch_bounds__(256, 3) void edge_kernel(
    const float* __restrict__ dvec, const float* __restrict__ x_edge,
    const int*   __restrict__ eidx, const int* __restrict__ batch,
    const int*   __restrict__ ecnt,
    const float* __restrict__ W1, const float* __restrict__ b1,
    const float* __restrict__ W2, const float* __restrict__ b2,
    float* __restrict__ repsum, int E)
{
    __shared__ float bins[192];   // [0,96) real, [96,192) dummy
    __shared__ f32x4 sb1N4[16], sw24[16], sw2b4[16];   // 16B-aligned constant banks
    float* sb1Nf = (float*)sb1N4;
    float* sw2f  = (float*)sw24;
    float* sw2bf = (float*)sw2b4;
    const int tid = threadIdx.x;
    const float NL2E = -1.442695040888963f;  // -log2(e)
    if (tid < 192) bins[tid] = 0.f;
    if (tid < 64) {
        float b = b1[tid], w = W2[tid];
        sb1Nf[tid] = b * NL2E;   // pre-folded exp2 bias
        sw2f[tid]  = w;
        sw2bf[tid] = w * b;      // pre-folded w2*z bias
    }
    __syncthreads();

    const int lane = tid & 63, wave = tid >> 6;
    const int col  = lane & 15, quad = lane >> 4;
    const long ebase = (long)blockIdx.x * 256 + wave * 64;

    // --- Prologue 1: scatter-metadata chain issued early, ALL lanes
    // (e depends only on col; quads 2/3 hit identical addresses).
    int nn[4];
    #pragma unroll
    for (int nt = 0; nt < 4; ++nt) {
        long e = ebase + nt * 16 + col;
        if (e >= E) e = 0;
        nn[nt] = eidx[e];
    }

    // --- Prologue 2: A fragments (W1 is 16KB, L2-hot).
    // A[m=mt*16+col][k=kt*32+quad*8+j] = W1[k][m]  (bf16 RNE)
    BF8 Af[4][2];
    #pragma unroll
    for (int mt = 0; mt < 4; ++mt)
        #pragma unroll
        for (int kt = 0; kt < 2; ++kt) {
            const float* wp = W1 + (kt * 32 + quad * 8) * 64 + mt * 16 + col;
            #pragma unroll
            for (int j = 0; j < 8; ++j) Af[mt][kt].s[j] = f2bf(wp[j * 64]);
        }

    // --- Prologue 3: resolve metadata; per-nt scatter base (branchless).
    // quads 0/1: tb = g*6 + quad*3 (real). quads 2/3: dummy slot.
    float scl[4];
    int   tb[4];
    const int dummy = 96 + (lane & 31) * 3;   // 96..189
    #pragma unroll
    for (int nt = 0; nt < 4; ++nt) {
        long e = ebase + nt * 16 + col;
        float s = __builtin_amdgcn_rcpf((float)max(ecnt[nn[nt]], 1));
        scl[nt] = (e < E) ? s : 0.f;
        int g   = batch[nn[nt]];
        tb[nt]  = (quad < 2) ? (g * 6 + quad * 3) : dummy;
    }

    const float bb2 = b2[0];

// Issue x/dvec loads for sub-tile NT into one stage register set (19 regs).
#define PIPE_ISSUE(NT, XA, XB, XC, XD, DD0, DD1, DD2)                          \
    {                                                                          \
        long e_ = ebase + (NT) * 16 + col;                                     \
        if (e_ >= E) e_ = 0;                                                   \
        const float* xp_ = x_edge + (size_t)e_ * EMB + quad * 8;               \
        XA = *(const f32x4*)(xp_);                                             \
        XB = *(const f32x4*)(xp_ + 4);                                         \
        XC = *(const f32x4*)(xp_ + 32);                                        \
        XD = *(const f32x4*)(xp_ + 36);                                        \
        DD0 = dvec[3 * e_ + 0];                                                \
        DD1 = dvec[3 * e_ + 1];                                                \
        DD2 = dvec[3 * e_ + 2];                                                \
    }

// Consume one stage; PRE (next stage's PIPE_ISSUE) sits after the B
// conversion so its load latency hides under the MFMA+silu block.
// Constants fetched as 3x ds_read_b128 per mt (vs 12x ds_read_b32).
#define PIPE_BODY(NT, XA, XB, XC, XD, DD0, DD1, DD2, PRE)                      \
    {                                                                          \
        BF8 B0_, B1_;                                                          \
        B0_.u[0] = cvt2(XA.x, XA.y); B0_.u[1] = cvt2(XA.z, XA.w);              \
        B0_.u[2] = cvt2(XB.x, XB.y); B0_.u[3] = cvt2(XB.z, XB.w);              \
        B1_.u[0] = cvt2(XC.x, XC.y); B1_.u[1] = cvt2(XC.z, XC.w);              \
        B1_.u[2] = cvt2(XD.x, XD.y); B1_.u[3] = cvt2(XD.z, XD.w);              \
        float a_[6] = { DD0*DD0, DD1*DD1, DD2*DD2, DD0*DD1, DD0*DD2, DD1*DD2 };\
        float aN_[6];                                                          \
        _Pragma("unroll")                                                      \
        for (int c = 0; c < 6; ++c) aN_[c] = a_[c] * NL2E;                     \
        PRE                                                                    \
        float acc_[6] = { 0.f, 0.f, 0.f, 0.f, 0.f, 0.f };                      \
        _Pragma("unroll")                                                      \
        for (int mt = 0; mt < 4; ++mt) {                                       \
            f32x4 D_ = { 0.f, 0.f, 0.f, 0.f };                                 \
            D_ = __builtin_amdgcn_mfma_f32_16x16x32_bf16(Af[mt][0].v, B0_.v, D_, 0, 0, 0); \
            D_ = __builtin_amdgcn_mfma_f32_16x16x32_bf16(Af[mt][1].v, B1_.v, D_, 0, 0, 0); \
            f32x4 bN4_ = sb1N4[mt * 4 + quad];                                 \
            f32x4 w24_ = sw24 [mt * 4 + quad];                                 \
            f32x4 wb4_ = sw2b4[mt * 4 + quad];                                 \
            _Pragma("unroll")                                                  \
            for (int r = 0; r < 4; ++r) {                                      \
                float y_  = D_[r];                                             \
                float bN_ = bN4_[r];                                           \
                float wy_ = w24_[r] * y_;                                      \
                float wb_ = wb4_[r];                                           \
                _Pragma("unroll")                                              \
                for (int c = 0; c < 6; ++c) {                                  \
                    float arg_ = fmaf(aN_[c], y_, bN_);                        \
                    float ex_  = __builtin_amdgcn_exp2f(arg_);                 \
                    float rr_  = __builtin_amdgcn_rcpf(1.0f + ex_);            \
                    float w2z_ = fmaf(a_[c], wy_, wb_);                        \
                    acc_[c]    = fmaf(w2z_, rr_, acc_[c]);                     \
                }                                                              \
            }                                                                  \
        }                                                                      \
        _Pragma("unroll")                                                      \
        for (int c = 0; c < 6; ++c) {                                          \
            acc_[c] += __shfl_xor(acc_[c], 16, 64);                            \
            acc_[c] += __shfl_xor(acc_[c], 32, 64);                            \
        }                                                                      \
        const int c0_ = (quad & 1) * 3;                                        \
        _Pragma("unroll")                                                      \
        for (int j = 0; j < 3; ++j)                                            \
            atomicAdd(&bins[tb[NT] + j], (acc_[c0_ + j] + bb2) * scl[NT]);     \
    }

    f32x4 Pxa, Pxb, Pxc, Pxd; float Pd0, Pd1, Pd2;
    f32x4 Qxa, Qxb, Qxc, Qxd; float Qd0, Qd1, Qd2;

    PIPE_ISSUE(0, Pxa, Pxb, Pxc, Pxd, Pd0, Pd1, Pd2)
    PIPE_BODY(0, Pxa, Pxb, Pxc, Pxd, Pd0, Pd1, Pd2,
              PIPE_ISSUE(1, Qxa, Qxb, Qxc, Qxd, Qd0, Qd1, Qd2))
    PIPE_BODY(1, Qxa, Qxb, Qxc, Qxd, Qd0, Qd1, Qd2,
              PIPE_ISSUE(2, Pxa, Pxb, Pxc, Pxd, Pd0, Pd1, Pd2))
    PIPE_BODY(2, Pxa, Pxb, Pxc, Pxd, Pd0, Pd1, Pd2,
              PIPE_ISSUE(3, Qxa, Qxb, Qxc, Qxd, Qd0, Qd1, Qd2))
    PIPE_BODY(3, Qxa, Qxb, Qxc, Qxd, Qd0, Qd1, Qd2, )

#undef PIPE_ISSUE
#undef PIPE_BODY

    __syncthreads();
    if (tid < 96) {
        int rep = blockIdx.x & (NREP - 1);
        atomicAdd(repsum + (size_t)rep * 96 + tid, bins[tid]);
    }
}

// ---------------------------------------------------------------------------
// Final: sum replicas (4-way parallel over reps); graph boundaries via
// binary search on the sorted batch array; divide by node count; expand 6
// symmetric comps -> 9.
// ---------------------------------------------------------------------------
__global__ __launch_bounds__(384) void final_kernel(
    const float* __restrict__ repsum, const int* __restrict__ batch,
    float* __restrict__ out, int N)
{
    __shared__ float part[4][96];
    __shared__ float sh[96];
    __shared__ int gs[17];
    int t = threadIdx.x;            // 384 threads
    int r0 = t / 96, gc = t % 96;   // r0 in 0..3
    if (t < 17) {
        // lower_bound: first i with batch[i] >= t  (batch sorted, 16 graphs)
        int lo = 0, hi = N;
        while (lo < hi) {
            int mid = (lo + hi) >> 1;
            if (batch[mid] < t) lo = mid + 1; else hi = mid;
        }
        gs[t] = lo;
    }
    float s = 0.f;
    #pragma unroll 8
    for (int r = r0; r < NREP; r += 4) s += repsum[(size_t)r * 96 + gc];
    part[r0][gc] = s;
    __syncthreads();
    if (t < 96) sh[t] = part[0][t] + part[1][t] + part[2][t] + part[3][t];
    __syncthreads();
    if (t < 16) {
        int gN = gs[t + 1] - gs[t];
        float inv = 1.0f / fmaxf((float)gN, 1.0f);
        float m0 = sh[t * 6 + 0] * inv;
        float m1 = sh[t * 6 + 1] * inv;
        float m2 = sh[t * 6 + 2] * inv;
        float m3 = sh[t * 6 + 3] * inv;
        float m4 = sh[t * 6 + 4] * inv;
        float m5 = sh[t * 6 + 5] * inv;
        float* p = out + t * 9;
        p[0] = m0; p[1] = m3; p[2] = m4;
        p[3] = m3; p[4] = m1; p[5] = m5;
        p[6] = m4; p[7] = m5; p[8] = m2;
    }
}

// ---------------------------------------------------------------------------
extern "C" void kernel_launch(void* const* d_in, const int* in_sizes, int n_in,
                              void* d_out, int out_size, void* d_ws, size_t ws_size,
                              hipStream_t stream) {
    const float* dvec   = (const float*)d_in[0];   // [E,3]
    const float* x_edge = (const float*)d_in[1];   // [E,64]
    const int*   eidx   = (const int*)d_in[2];     // [E]
    const int*   batch  = (const int*)d_in[3];     // [N] sorted
    const float* W1     = (const float*)d_in[6];   // [64,64] (in,out)
    const float* b1     = (const float*)d_in[7];   // [64]
    const float* W2     = (const float*)d_in[8];   // [64,1]
    const float* b2     = (const float*)d_in[9];   // [1]

    int E = in_sizes[0] / 3;   // 800000
    int N = in_sizes[3];       // 50000

    // ws: ecnt[N] int | repsum[NREP*96] float  (contiguous)
    int*   ecnt   = (int*)d_ws;
    float* repsum = (float*)(ecnt + N);

    hipMemsetAsync(d_ws, 0, ((size_t)N + (size_t)NREP * 96) * 4, stream);

    int blocks = (E + 255) / 256;   // 3125
    prep_kernel<<<blocks, 256, 0, stream>>>(eidx, ecnt, E);
    edge_kernel<<<blocks, 256, 0, stream>>>(dvec, x_edge, eidx, batch, ecnt,
                                            W1, b1, W2, b2, repsum, E);
    final_kernel<<<1, 384, 0, stream>>>(repsum, batch, (float*)d_out, N);
}

// Round 13
// 371.566 us; speedup vs baseline: 1.0845x; 1.0254x over previous
//
#include <hip/hip_runtime.h>

// Problem constants: E=800000 (=3125*256), N=50000, G=16, EMB=64.
#define EMB  64
#define NREP 256   // replica lines for per-graph global atomic spreading

typedef __attribute__((ext_vector_type(8))) short bf16x8;
typedef __attribute__((ext_vector_type(4))) float f32x4;
typedef __attribute__((ext_vector_type(2))) float f32x2;
union BF8 { bf16x8 v; short s[8]; unsigned u[4]; };

// float -> bf16 bits, round-to-nearest-even (finite inputs).
static __device__ __forceinline__ short f2bf(float f) {
    unsigned u = __float_as_uint(f);
    u += 0x7fffu + ((u >> 16) & 1u);
    return (short)(u >> 16);
}

// 2x float -> packed bf16 pair in one instruction (RNE, bit-identical to f2bf).
static __device__ __forceinline__ unsigned cvt2(float lo, float hi) {
    unsigned r;
    asm("v_cvt_pk_bf16_f32 %0, %1, %2" : "=v"(r) : "v"(lo), "v"(hi));
    return r;
}

// ---------------------------------------------------------------------------
// Prep: ecnt histogram, scalar 1-edge/thread (validated form).
// ---------------------------------------------------------------------------
__global__ __launch_bounds__(256) void prep_kernel(
    const int* __restrict__ eidx, int* __restrict__ ecnt, int E)
{
    int t = blockIdx.x * 256 + threadIdx.x;
    if (t < E) atomicAdd(&ecnt[eidx[t]], 1);
}

// ---------------------------------------------------------------------------
// Edge kernel v13 = v11 (validated: 125.7us, VALUBusy 58%, VGPR 84, no
// spill) + packed-f32x2 silu inner loop, SAME algebra (aN precomputed) so
// per-lane ops are bit-identical -> absmax must stay 1.2207e-4 exactly.
//
// NaN ROOT CAUSE (R12 unified): every NaN config had natural register
// pressure > launch_bounds cap (v5 ~190>168; v8 ~170>128; v12 ~170 after
// LICM re-hoisted the "LDS-moved" Af reads >128). Forced-squeeze spill
// around this cvt2+MFMA body miscompiles. RULE: (256,3) only, no caps,
// pressure must stay under ~168. Packed-f32x2 alone adds ~6 temps over
// v11 -- fits. (v5's NaN came from its +32-reg cb/cw arrays, bundled.)
// Occupancy lever (4 waves/SIMD) permanently closed.
// ---------------------------------------------------------------------------
__global__ __launch_bounds__(256, 3) void edge_kernel(
    const float* __restrict__ dvec, const float* __restrict__ x_edge,
    const int*   __restrict__ eidx, const int* __restrict__ batch,
    const int*   __restrict__ ecnt,
    const float* __restrict__ W1, const float* __restrict__ b1,
    const float* __restrict__ W2, const float* __restrict__ b2,
    float* __restrict__ repsum, int E)
{
    __shared__ float bins[192];   // [0,96) real, [96,192) dummy
    __shared__ f32x4 sb1N4[16], sw24[16], sw2b4[16];   // 16B constant banks
    float* sb1Nf = (float*)sb1N4;
    float* sw2f  = (float*)sw24;
    float* sw2bf = (float*)sw2b4;
    const int tid = threadIdx.x;
    const float NL2E = -1.442695040888963f;  // -log2(e)
    if (tid < 192) bins[tid] = 0.f;
    if (tid < 64) {
        float b = b1[tid], w = W2[tid];
        sb1Nf[tid] = b * NL2E;   // pre-folded exp2 bias
        sw2f[tid]  = w;
        sw2bf[tid] = w * b;      // pre-folded w2*z bias
    }
    __syncthreads();

    const int lane = tid & 63, wave = tid >> 6;
    const int col  = lane & 15, quad = lane >> 4;
    const long ebase = (long)blockIdx.x * 256 + wave * 64;

    // --- Prologue 1: scatter-metadata chain issued early, ALL lanes
    // (e depends only on col; quads 2/3 hit identical addresses).
    int nn[4];
    #pragma unroll
    for (int nt = 0; nt < 4; ++nt) {
        long e = ebase + nt * 16 + col;
        if (e >= E) e = 0;
        nn[nt] = eidx[e];
    }

    // --- Prologue 2: A fragments (W1 is 16KB, L2-hot).
    // A[m=mt*16+col][k=kt*32+quad*8+j] = W1[k][m]  (bf16 RNE)
    BF8 Af[4][2];
    #pragma unroll
    for (int mt = 0; mt < 4; ++mt)
        #pragma unroll
        for (int kt = 0; kt < 2; ++kt) {
            const float* wp = W1 + (kt * 32 + quad * 8) * 64 + mt * 16 + col;
            #pragma unroll
            for (int j = 0; j < 8; ++j) Af[mt][kt].s[j] = f2bf(wp[j * 64]);
        }

    // --- Prologue 3: resolve metadata; per-nt scatter base (branchless).
    // quads 0/1: tb = g*6 + quad*3 (real). quads 2/3: dummy slot.
    float scl[4];
    int   tb[4];
    const int dummy = 96 + (lane & 31) * 3;   // 96..189
    #pragma unroll
    for (int nt = 0; nt < 4; ++nt) {
        long e = ebase + nt * 16 + col;
        float s = __builtin_amdgcn_rcpf((float)max(ecnt[nn[nt]], 1));
        scl[nt] = (e < E) ? s : 0.f;
        int g   = batch[nn[nt]];
        tb[nt]  = (quad < 2) ? (g * 6 + quad * 3) : dummy;
    }

    const float bb2 = b2[0];
    const f32x2 vONE = { 1.0f, 1.0f };

// Issue x/dvec loads for sub-tile NT into one stage register set (19 regs).
#define PIPE_ISSUE(NT, XA, XB, XC, XD, DD0, DD1, DD2)                          \
    {                                                                          \
        long e_ = ebase + (NT) * 16 + col;                                     \
        if (e_ >= E) e_ = 0;                                                   \
        const float* xp_ = x_edge + (size_t)e_ * EMB + quad * 8;               \
        XA = *(const f32x4*)(xp_);                                             \
        XB = *(const f32x4*)(xp_ + 4);                                         \
        XC = *(const f32x4*)(xp_ + 32);                                        \
        XD = *(const f32x4*)(xp_ + 36);                                        \
        DD0 = dvec[3 * e_ + 0];                                                \
        DD1 = dvec[3 * e_ + 1];                                                \
        DD2 = dvec[3 * e_ + 2];                                                \
    }

// Consume one stage; PRE (next stage's PIPE_ISSUE) sits after the B
// conversion so its load latency hides under the MFMA+silu block.
// Silu inner loop packed as f32x2 over component pairs (same per-lane fma/
// exp2/rcp sequence as v11 -> bit-identical results, ~half the VALU issue).
#define PIPE_BODY(NT, XA, XB, XC, XD, DD0, DD1, DD2, PRE)                      \
    {                                                                          \
        BF8 B0_, B1_;                                                          \
        B0_.u[0] = cvt2(XA.x, XA.y); B0_.u[1] = cvt2(XA.z, XA.w);              \
        B0_.u[2] = cvt2(XB.x, XB.y); B0_.u[3] = cvt2(XB.z, XB.w);              \
        B1_.u[0] = cvt2(XC.x, XC.y); B1_.u[1] = cvt2(XC.z, XC.w);              \
        B1_.u[2] = cvt2(XD.x, XD.y); B1_.u[3] = cvt2(XD.z, XD.w);              \
        f32x2 ap2_[3], aN2_[3];                                                \
        ap2_[0].x = DD0 * DD0; ap2_[0].y = DD1 * DD1;                          \
        ap2_[1].x = DD2 * DD2; ap2_[1].y = DD0 * DD1;                          \
        ap2_[2].x = DD0 * DD2; ap2_[2].y = DD1 * DD2;                          \
        _Pragma("unroll")                                                      \
        for (int p = 0; p < 3; ++p) {                                          \
            aN2_[p].x = ap2_[p].x * NL2E;                                      \
            aN2_[p].y = ap2_[p].y * NL2E;                                      \
        }                                                                      \
        PRE                                                                    \
        f32x2 acc2_[3];                                                        \
        acc2_[0] = (f32x2){0.f, 0.f}; acc2_[1] = (f32x2){0.f, 0.f};            \
        acc2_[2] = (f32x2){0.f, 0.f};                                          \
        _Pragma("unroll")                                                      \
        for (int mt = 0; mt < 4; ++mt) {                                       \
            f32x4 D_ = { 0.f, 0.f, 0.f, 0.f };                                 \
            D_ = __builtin_amdgcn_mfma_f32_16x16x32_bf16(Af[mt][0].v, B0_.v, D_, 0, 0, 0); \
            D_ = __builtin_amdgcn_mfma_f32_16x16x32_bf16(Af[mt][1].v, B1_.v, D_, 0, 0, 0); \
            f32x4 bN4_ = sb1N4[mt * 4 + quad];                                 \
            f32x4 w24_ = sw24 [mt * 4 + quad];                                 \
            f32x4 wb4_ = sw2b4[mt * 4 + quad];                                 \
            _Pragma("unroll")                                                  \
            for (int r = 0; r < 4; ++r) {                                      \
                float y_  = D_[r];                                             \
                float wy_ = w24_[r] * y_;                                      \
                f32x2 y2_  = { y_, y_ };                                       \
                f32x2 bN2_ = { bN4_[r], bN4_[r] };                             \
                f32x2 wy2_ = { wy_, wy_ };                                     \
                f32x2 wb2_ = { wb4_[r], wb4_[r] };                             \
                _Pragma("unroll")                                              \
                for (int p = 0; p < 3; ++p) {                                  \
                    f32x2 arg_ = aN2_[p] * y2_ + bN2_;    /* pk_fma */         \
                    f32x2 ex_;                                                 \
                    ex_.x = __builtin_amdgcn_exp2f(arg_.x);                    \
                    ex_.y = __builtin_amdgcn_exp2f(arg_.y);                    \
                    f32x2 dn_ = ex_ + vONE;               /* pk_add */         \
                    f32x2 rr_;                                                 \
                    rr_.x = __builtin_amdgcn_rcpf(dn_.x);                      \
                    rr_.y = __builtin_amdgcn_rcpf(dn_.y);                      \
                    f32x2 wz_ = ap2_[p] * wy2_ + wb2_;    /* pk_fma */         \
                    acc2_[p] = wz_ * rr_ + acc2_[p];      /* pk_fma */         \
                }                                                              \
            }                                                                  \
        }                                                                      \
        float a6_[6] = { acc2_[0].x, acc2_[0].y, acc2_[1].x,                   \
                         acc2_[1].y, acc2_[2].x, acc2_[2].y };                 \
        _Pragma("unroll")                                                      \
        for (int c = 0; c < 6; ++c) {                                          \
            a6_[c] += __shfl_xor(a6_[c], 16, 64);                              \
            a6_[c] += __shfl_xor(a6_[c], 32, 64);                              \
        }                                                                      \
        const int c0_ = (quad & 1) * 3;                                        \
        _Pragma("unroll")                                                      \
        for (int j = 0; j < 3; ++j)                                            \
            atomicAdd(&bins[tb[NT] + j], (a6_[c0_ + j] + bb2) * scl[NT]);      \
    }

    f32x4 Pxa, Pxb, Pxc, Pxd; float Pd0, Pd1, Pd2;
    f32x4 Qxa, Qxb, Qxc, Qxd; float Qd0, Qd1, Qd2;

    PIPE_ISSUE(0, Pxa, Pxb, Pxc, Pxd, Pd0, Pd1, Pd2)
    PIPE_BODY(0, Pxa, Pxb, Pxc, Pxd, Pd0, Pd1, Pd2,
              PIPE_ISSUE(1, Qxa, Qxb, Qxc, Qxd, Qd0, Qd1, Qd2))
    PIPE_BODY(1, Qxa, Qxb, Qxc, Qxd, Qd0, Qd1, Qd2,
              PIPE_ISSUE(2, Pxa, Pxb, Pxc, Pxd, Pd0, Pd1, Pd2))
    PIPE_BODY(2, Pxa, Pxb, Pxc, Pxd, Pd0, Pd1, Pd2,
              PIPE_ISSUE(3, Qxa, Qxb, Qxc, Qxd, Qd0, Qd1, Qd2))
    PIPE_BODY(3, Qxa, Qxb, Qxc, Qxd, Qd0, Qd1, Qd2, )

#undef PIPE_ISSUE
#undef PIPE_BODY

    __syncthreads();
    if (tid < 96) {
        int rep = blockIdx.x & (NREP - 1);
        atomicAdd(repsum + (size_t)rep * 96 + tid, bins[tid]);
    }
}

// ---------------------------------------------------------------------------
// Final: sum replicas (4-way parallel over reps); graph boundaries via
// binary search on the sorted batch array; divide by node count; expand 6
// symmetric comps -> 9.
// ---------------------------------------------------------------------------
__global__ __launch_bounds__(384) void final_kernel(
    const float* __restrict__ repsum, const int* __restrict__ batch,
    float* __restrict__ out, int N)
{
    __shared__ float part[4][96];
    __shared__ float sh[96];
    __shared__ int gs[17];
    int t = threadIdx.x;            // 384 threads
    int r0 = t / 96, gc = t % 96;   // r0 in 0..3
    if (t < 17) {
        // lower_bound: first i with batch[i] >= t  (batch sorted, 16 graphs)
        int lo = 0, hi = N;
        while (lo < hi) {
            int mid = (lo + hi) >> 1;
            if (batch[mid] < t) lo = mid + 1; else hi = mid;
        }
        gs[t] = lo;
    }
    float s = 0.f;
    #pragma unroll 8
    for (int r = r0; r < NREP; r += 4) s += repsum[(size_t)r * 96 + gc];
    part[r0][gc] = s;
    __syncthreads();
    if (t < 96) sh[t] = part[0][t] + part[1][t] + part[2][t] + part[3][t];
    __syncthreads();
    if (t < 16) {
        int gN = gs[t + 1] - gs[t];
        float inv = 1.0f / fmaxf((float)gN, 1.0f);
        float m0 = sh[t * 6 + 0] * inv;
        float m1 = sh[t * 6 + 1] * inv;
        float m2 = sh[t * 6 + 2] * inv;
        float m3 = sh[t * 6 + 3] * inv;
        float m4 = sh[t * 6 + 4] * inv;
        float m5 = sh[t * 6 + 5] * inv;
        float* p = out + t * 9;
        p[0] = m0; p[1] = m3; p[2] = m4;
        p[3] = m3; p[4] = m1; p[5] = m5;
        p[6] = m4; p[7] = m5; p[8] = m2;
    }
}

// ---------------------------------------------------------------------------
extern "C" void kernel_launch(void* const* d_in, const int* in_sizes, int n_in,
                              void* d_out, int out_size, void* d_ws, size_t ws_size,
                              hipStream_t stream) {
    const float* dvec   = (const float*)d_in[0];   // [E,3]
    const float* x_edge = (const float*)d_in[1];   // [E,64]
    const int*   eidx   = (const int*)d_in[2];     // [E]
    const int*   batch  = (const int*)d_in[3];     // [N] sorted
    const float* W1     = (const float*)d_in[6];   // [64,64] (in,out)
    const float* b1     = (const float*)d_in[7];   // [64]
    const float* W2     = (const float*)d_in[8];   // [64,1]
    const float* b2     = (const float*)d_in[9];   // [1]

    int E = in_sizes[0] / 3;   // 800000
    int N = in_sizes[3];       // 50000

    // ws: ecnt[N] int | repsum[NREP*96] float  (contiguous)
    int*   ecnt   = (int*)d_ws;
    float* repsum = (float*)(ecnt + N);

    hipMemsetAsync(d_ws, 0, ((size_t)N + (size_t)NREP * 96) * 4, stream);

    int blocks = (E + 255) / 256;   // 3125
    prep_kernel<<<blocks, 256, 0, stream>>>(eidx, ecnt, E);
    edge_kernel<<<blocks, 256, 0, stream>>>(dvec, x_edge, eidx, batch, ecnt,
                                            W1, b1, W2, b2, repsum, E);
    final_kernel<<<1, 384, 0, stream>>>(repsum, batch, (float*)d_out, N);
}